// Round 1
// baseline (18394.208 us; speedup 1.0000x reference)
//
#include <hip/hip_runtime.h>
#include <cstdint>
#include <cstddef>

// LayerNormLSTM on MI355X.
// Phase 0: fp32->bf16 conversion of x, Wi, Wh, hx.
// Phase 1: Gpre = x @ Wi^T  (bf16 MFMA 16x16x32, 128x128 tiles).
// Phase 1.5: in-place row LN (scale=b1, shift=s1) over the 2048 gate dim.
// Phase 2: persistent recurrence. 64 wgs = 4 teams(16 samples) x 16 slices.
//   Each wg holds its 128 rows of Wh as MFMA B-fragments in registers.
//   Per step: MFMA [16x512]@[512x128] -> cross-wg LN stats (2048) ->
//   activations -> cross-wg LN stats (512) -> c,h update -> h broadcast.
//   Cross-wg sync: monotone per-team counters (device scope), parity-
//   double-buffered stat slots; plain stores + __threadfence + release add,
//   acquire spin loads on the read side.

typedef float  f32x4 __attribute__((ext_vector_type(4)));
typedef __bf16 bf16x8 __attribute__((ext_vector_type(8)));
typedef unsigned int u32x4 __attribute__((ext_vector_type(4)));
typedef unsigned short u16x4 __attribute__((ext_vector_type(4)));

#define DEV __device__ __forceinline__

DEV unsigned short f2b(float f){
  unsigned int u = __builtin_bit_cast(unsigned int, f);
  unsigned int r = (u + 0x7FFFu + ((u >> 16) & 1u)) >> 16;
  return (unsigned short)r;
}
DEV float b2f(unsigned short s){
  unsigned int u = ((unsigned int)s) << 16;
  return __builtin_bit_cast(float, u);
}

DEV void wait_ge(unsigned int* p, unsigned int target){
  while (true){
    unsigned int v = 0;
    if ((threadIdx.x & 63) == 0)
      v = __hip_atomic_load(p, __ATOMIC_ACQUIRE, __HIP_MEMORY_SCOPE_AGENT);
    v = (unsigned int)__builtin_amdgcn_readfirstlane((int)v);
    if (v >= target) break;
    __builtin_amdgcn_s_sleep(1);
  }
}

// ---------------- Phase 0: conversion ----------------
__global__ __launch_bounds__(256) void conv_bf16(const float* __restrict__ src,
                                                 unsigned short* __restrict__ dst,
                                                 int n4){
  int i = blockIdx.x * 256 + threadIdx.x;
  if (i >= n4) return;
  f32x4 v = ((const f32x4*)src)[i];
  u16x4 o;
  #pragma unroll
  for (int j = 0; j < 4; ++j) o[j] = f2b(v[j]);
  ((u16x4*)dst)[i] = o;
}

// ---------------- Phase 1: Gpre = Xb @ Wib^T ----------------
// Xb [32768][512] bf16, Wib [2048][512] bf16, Gp [32768][2048] bf16.
__global__ __launch_bounds__(256, 2) void gemm_gi(const unsigned short* __restrict__ Xb,
                                                  const unsigned short* __restrict__ Wib,
                                                  unsigned short* __restrict__ Gp){
  __shared__ unsigned short As[128 * 48];  // stride 48 keeps 16B align, <=4-way conflicts
  __shared__ unsigned short Bs[128 * 48];
  const int tid = threadIdx.x;
  const int m0 = blockIdx.x * 128;
  const int n0 = blockIdx.y * 128;
  const int w = tid >> 6, lane = tid & 63;
  const int lr = lane & 15, lq = lane >> 4;
  const int wm = (w & 1) * 64, wn = (w >> 1) * 64;
  const int sr = tid >> 2;           // 0..63
  const int sc = (tid & 3) * 8;      // 0,8,16,24
  const unsigned short* gx = Xb + (size_t)(m0 + sr) * 512 + sc;
  const unsigned short* gw = Wib + (size_t)(n0 + sr) * 512 + sc;
  f32x4 acc[4][4] = {};
  for (int kb = 0; kb < 16; ++kb){
    u32x4 a0 = *(const u32x4*)(gx + kb * 32);
    u32x4 a1 = *(const u32x4*)(gx + 64 * 512 + kb * 32);
    u32x4 b0 = *(const u32x4*)(gw + kb * 32);
    u32x4 b1 = *(const u32x4*)(gw + 64 * 512 + kb * 32);
    __syncthreads();
    *(u32x4*)&As[sr * 48 + sc] = a0;
    *(u32x4*)&As[(sr + 64) * 48 + sc] = a1;
    *(u32x4*)&Bs[sr * 48 + sc] = b0;
    *(u32x4*)&Bs[(sr + 64) * 48 + sc] = b1;
    __syncthreads();
    bf16x8 af[4], bfv[4];
    #pragma unroll
    for (int mi = 0; mi < 4; ++mi) af[mi] = *(const bf16x8*)&As[(wm + mi * 16 + lr) * 48 + lq * 8];
    #pragma unroll
    for (int ni = 0; ni < 4; ++ni) bfv[ni] = *(const bf16x8*)&Bs[(wn + ni * 16 + lr) * 48 + lq * 8];
    #pragma unroll
    for (int mi = 0; mi < 4; ++mi)
      #pragma unroll
      for (int ni = 0; ni < 4; ++ni)
        acc[mi][ni] = __builtin_amdgcn_mfma_f32_16x16x32_bf16(af[mi], bfv[ni], acc[mi][ni], 0, 0, 0);
  }
  // C/D layout: col = lane&15, row = (lane>>4)*4 + reg (m89-verified)
  #pragma unroll
  for (int mi = 0; mi < 4; ++mi){
    const int rowb = m0 + wm + mi * 16 + lq * 4;
    #pragma unroll
    for (int ni = 0; ni < 4; ++ni){
      const int col = n0 + wn + ni * 16 + lr;
      #pragma unroll
      for (int r = 0; r < 4; ++r)
        Gp[(size_t)(rowb + r) * 2048 + col] = f2b(acc[mi][ni][r]);
    }
  }
}

// ---------------- Phase 1.5: in-place LN of rows (scale=b1, shift=s1) ----------------
__global__ __launch_bounds__(256) void ln_rows(unsigned short* __restrict__ G,
                                               const float* __restrict__ b1,
                                               const float* __restrict__ s1){
  const int row = blockIdx.x;
  const int tid = threadIdx.x;
  unsigned short* rp = G + (size_t)row * 2048 + tid * 8;
  u32x4 raw = *(const u32x4*)rp;
  float x[8];
  #pragma unroll
  for (int j = 0; j < 8; ++j){
    unsigned int word = raw[j >> 1];
    unsigned short us = (j & 1) ? (unsigned short)(word >> 16) : (unsigned short)(word & 0xFFFF);
    x[j] = b2f(us);
  }
  float s = 0.f, q = 0.f;
  #pragma unroll
  for (int j = 0; j < 8; ++j){ s += x[j]; q += x[j] * x[j]; }
  #pragma unroll
  for (int o = 1; o < 64; o <<= 1){ s += __shfl_xor(s, o); q += __shfl_xor(q, o); }
  __shared__ float ps[4][2];
  const int wv = tid >> 6;
  if ((tid & 63) == 0){ ps[wv][0] = s; ps[wv][1] = q; }
  __syncthreads();
  s = ps[0][0] + ps[1][0] + ps[2][0] + ps[3][0];
  q = ps[0][1] + ps[1][1] + ps[2][1] + ps[3][1];
  const float mu = s * (1.f / 2048.f);
  const float inv = rsqrtf((q - s * mu) + 1e-5f);
  const float* b1p = b1 + tid * 8;
  const float* s1p = s1 + tid * 8;
  u32x4 outw;
  #pragma unroll
  for (int j = 0; j < 4; ++j){
    float y0 = b1p[2 * j]     * ((x[2 * j]     - mu) * inv) + s1p[2 * j];
    float y1 = b1p[2 * j + 1] * ((x[2 * j + 1] - mu) * inv) + s1p[2 * j + 1];
    outw[j] = (unsigned int)f2b(y0) | ((unsigned int)f2b(y1) << 16);
  }
  *(u32x4*)rp = outw;
}

// ---------------- Phase 2: persistent recurrence ----------------
__global__ __launch_bounds__(512, 2) void lstm_rec(
    const unsigned short* __restrict__ Gi,   // [32768][2048] bf16, post-LN gi
    const unsigned short* __restrict__ Whb,  // [2048][512] bf16
    const float* __restrict__ bias,
    const float* __restrict__ b2, const float* __restrict__ s2,
    const float* __restrict__ b3, const float* __restrict__ s3,
    const float* __restrict__ cx,
    unsigned short* __restrict__ hb,         // [2][64][512] bf16
    float* __restrict__ stA,                 // [2][4][16][16][2]
    float* __restrict__ stC,                 // [2][4][16][16][2]
    unsigned int* __restrict__ ctr,          // [0..3]=h, [4..7]=A, [8..11]=C
    float* __restrict__ out){
  const int tid = threadIdx.x;
  const int tm = blockIdx.x >> 4;          // team 0..3 (samples tm*16..+16)
  const int ks = blockIdx.x & 15;          // slice 0..15 (j in [ks*32, ks*32+32))
  const int w = tid >> 6;                  // wave 0..7
  const int lane = tid & 63;
  const int lr = lane & 15, lq = lane >> 4;

  // gate-wave constants: wave w owns rows type*512 + ks*32 + jloc, jloc=(w&1)*16+lr
  const int type = w >> 1;                 // 0=i 1=f 2=g 3=o
  const int jloc = (w & 1) * 16 + lr;      // 0..31
  const int row_g = type * 512 + ks * 32 + jloc;
  const float b2r = b2[row_g];
  const float sbr = s2[row_g] + bias[row_g];

  // Wh B-fragments in registers (B layout: n=lane&15, k=(lane>>4)*8+j)
  bf16x8 bfr[16];
  {
    const unsigned short* wr = Whb + (size_t)row_g * 512 + lq * 8;
    #pragma unroll
    for (int kk = 0; kk < 16; ++kk) bfr[kk] = *(const bf16x8*)(wr + kk * 32);
  }

  // c-phase constants: thread -> (sample cs0, feature j=ks*32+cj)
  const int cs0 = tid & 15;
  const int cj = tid >> 4;                 // 0..31
  const int hcol = ks * 32 + cj;
  float c_val = cx[(size_t)(tm * 16 + cs0) * 512 + hcol];
  const float b3j = b3[hcol], s3j = s3[hcol];

  __shared__ float act[4][32][17];
  __shared__ float redA[8][16][2];
  __shared__ float redC[8][16][2];
  __shared__ float stAl[16][2];
  __shared__ float stCl[16][2];

  unsigned int* cntH = ctr + tm;
  unsigned int* cntA = ctr + 4 + tm;
  unsigned int* cntC = ctr + 8 + tm;

  for (int t = 0; t < 512; ++t){
    const int par = t & 1;
    // gi prefetch for this step (independent of recurrence state)
    float giv[4];
    #pragma unroll
    for (int r = 0; r < 4; ++r){
      const int b = tm * 16 + lq * 4 + r;
      giv[r] = b2f(Gi[((size_t)b * 512 + t) * 2048 + row_g]);
    }
    // wait for h of step t
    wait_ge(cntH, 16u * (unsigned)t);
    // A-frags from h broadcast (A layout: m=lane&15, k=(lane>>4)*8+j)
    const unsigned short* hp = hb + par * 32768 + (size_t)(tm * 16 + lr) * 512 + lq * 8;
    bf16x8 af[16];
    #pragma unroll
    for (int kk = 0; kk < 16; ++kk) af[kk] = *(const bf16x8*)(hp + kk * 32);
    f32x4 acc = {0.f, 0.f, 0.f, 0.f};
    #pragma unroll
    for (int kk = 0; kk < 16; ++kk)
      acc = __builtin_amdgcn_mfma_f32_16x16x32_bf16(af[kk], bfr[kk], acc, 0, 0, 0);
    // stats-a partials: per sample, sum over this wave's 16 gate cols
    float sa[4], qa[4];
    #pragma unroll
    for (int r = 0; r < 4; ++r){
      float s = acc[r], q = acc[r] * acc[r];
      #pragma unroll
      for (int o = 1; o < 16; o <<= 1){ s += __shfl_xor(s, o); q += __shfl_xor(q, o); }
      sa[r] = s; qa[r] = q;
    }
    if (lr == 0){
      #pragma unroll
      for (int r = 0; r < 4; ++r){ redA[w][lq * 4 + r][0] = sa[r]; redA[w][lq * 4 + r][1] = qa[r]; }
    }
    __syncthreads();
    float* slotA = stA + (size_t)(par * 4 + tm) * 512;
    if (tid < 16){
      float S = 0.f, Q = 0.f;
      #pragma unroll
      for (int w2 = 0; w2 < 8; ++w2){ S += redA[w2][tid][0]; Q += redA[w2][tid][1]; }
      slotA[(tid * 16 + ks) * 2 + 0] = S;
      slotA[(tid * 16 + ks) * 2 + 1] = Q;
      __threadfence();
    }
    __syncthreads();
    if (tid == 0) __hip_atomic_fetch_add(cntA, 1u, __ATOMIC_RELEASE, __HIP_MEMORY_SCOPE_AGENT);
    if (w == 0) wait_ge(cntA, 16u * (unsigned)(t + 1));
    if (tid < 16){
      float S = 0.f, Q = 0.f;
      #pragma unroll
      for (int k2 = 0; k2 < 16; ++k2){ S += slotA[(tid * 16 + k2) * 2]; Q += slotA[(tid * 16 + k2) * 2 + 1]; }
      const float mu = S * (1.f / 2048.f);
      stAl[tid][0] = mu;
      stAl[tid][1] = rsqrtf((Q - S * mu) + 1e-5f);
    }
    __syncthreads();
    // gates + activations
    #pragma unroll
    for (int r = 0; r < 4; ++r){
      const int s0 = lq * 4 + r;
      const float nv = (acc[r] - stAl[s0][0]) * stAl[s0][1];
      const float gv = giv[r] + b2r * nv + sbr;
      float a;
      if (type == 2) a = tanhf(gv);
      else           a = 1.f / (1.f + __expf(-gv));
      act[type][jloc][s0] = a;
    }
    __syncthreads();
    // c-candidate + stats-c partials
    const float i_g = act[0][cj][cs0];
    const float f_g = act[1][cj][cs0];
    const float g_g = act[2][cj][cs0];
    const float o_g = act[3][cj][cs0];
    const float cc = f_g * c_val + i_g * g_g;
    {
      float s = cc, q = cc * cc;
      s += __shfl_xor(s, 16); q += __shfl_xor(q, 16);
      s += __shfl_xor(s, 32); q += __shfl_xor(q, 32);
      if (lane < 16){ redC[w][lane][0] = s; redC[w][lane][1] = q; }
    }
    __syncthreads();
    float* slotC = stC + (size_t)(par * 4 + tm) * 512;
    if (tid < 16){
      float S = 0.f, Q = 0.f;
      #pragma unroll
      for (int w2 = 0; w2 < 8; ++w2){ S += redC[w2][tid][0]; Q += redC[w2][tid][1]; }
      slotC[(tid * 16 + ks) * 2 + 0] = S;
      slotC[(tid * 16 + ks) * 2 + 1] = Q;
      __threadfence();
    }
    __syncthreads();
    if (tid == 0) __hip_atomic_fetch_add(cntC, 1u, __ATOMIC_RELEASE, __HIP_MEMORY_SCOPE_AGENT);
    if (w == 0) wait_ge(cntC, 16u * (unsigned)(t + 1));
    if (tid < 16){
      float S = 0.f, Q = 0.f;
      #pragma unroll
      for (int k2 = 0; k2 < 16; ++k2){ S += slotC[(tid * 16 + k2) * 2]; Q += slotC[(tid * 16 + k2) * 2 + 1]; }
      const float mu = S * (1.f / 512.f);
      stCl[tid][0] = mu;
      stCl[tid][1] = rsqrtf((Q - S * mu) + 1e-5f);
    }
    __syncthreads();
    const float cn = b3j * ((cc - stCl[cs0][0]) * stCl[cs0][1]) + s3j;
    c_val = cn;
    const float h = o_g * tanhf(cn);
    const int bidx = tm * 16 + cs0;
    out[((size_t)bidx * 512 + t) * 512 + hcol] = h;
    if (t == 511){
      out[16777216u + (size_t)bidx * 512 + hcol] = h;
      out[16777216u + 32768u + (size_t)bidx * 512 + hcol] = cn;
    }
    hb[(1 - par) * 32768 + (size_t)bidx * 512 + hcol] = f2b(h);
    __threadfence();
    __syncthreads();
    if (tid == 0) __hip_atomic_fetch_add(cntH, 1u, __ATOMIC_RELEASE, __HIP_MEMORY_SCOPE_AGENT);
  }
}

extern "C" void kernel_launch(void* const* d_in, const int* in_sizes, int n_in,
                              void* d_out, int out_size, void* d_ws, size_t ws_size,
                              hipStream_t stream){
  (void)in_sizes; (void)n_in; (void)out_size; (void)ws_size;
  const float* x    = (const float*)d_in[0];
  const float* hx   = (const float*)d_in[1];
  const float* cx   = (const float*)d_in[2];
  const float* Wi   = (const float*)d_in[3];
  const float* Wh   = (const float*)d_in[4];
  const float* bias = (const float*)d_in[5];
  const float* b1   = (const float*)d_in[6];
  const float* b2   = (const float*)d_in[7];
  const float* b3   = (const float*)d_in[8];
  const float* s1   = (const float*)d_in[9];
  const float* s2   = (const float*)d_in[10];
  const float* s3   = (const float*)d_in[11];
  float* out = (float*)d_out;
  char* ws = (char*)d_ws;

  unsigned short* xb  = (unsigned short*)(ws);                 // 33,554,432 B
  unsigned short* wib = (unsigned short*)(ws + 33554432);      //  2,097,152 B
  unsigned short* whb = (unsigned short*)(ws + 35651584);      //  2,097,152 B
  unsigned short* gp  = (unsigned short*)(ws + 37748736);      // 134,217,728 B
  unsigned short* hb  = (unsigned short*)(ws + 171966464);     //    131,072 B
  float*        stA   = (float*)(ws + 172097536);              //     16,384 B
  float*        stC   = (float*)(ws + 172113920);              //     16,384 B
  unsigned int* ctr   = (unsigned int*)(ws + 172130304);       //         64 B

  conv_bf16<<<16384, 256, 0, stream>>>(x,  xb,  4194304);
  conv_bf16<<<1024,  256, 0, stream>>>(Wi, wib, 262144);
  conv_bf16<<<1024,  256, 0, stream>>>(Wh, whb, 262144);
  conv_bf16<<<32,    256, 0, stream>>>(hx, hb,  8192);   // h broadcast slot 0
  hipMemsetAsync(ctr, 0, 64, stream);
  gemm_gi<<<dim3(256, 16, 1), 256, 0, stream>>>(xb, wib, gp);
  ln_rows<<<32768, 256, 0, stream>>>(gp, b1, s1);
  lstm_rec<<<64, 512, 0, stream>>>(gp, whb, bias, b2, s2, b3, s3, cx,
                                   hb, stA, stC, ctr, out);
}

// Round 2
// 12372.778 us; speedup vs baseline: 1.4867x; 1.4867x over previous
//
#include <hip/hip_runtime.h>
#include <cstdint>
#include <cstddef>

// LayerNormLSTM on MI355X.
// Phase 0: fp32->bf16 conversion of x, Wi, Wh, hx.
// Phase 1: Gpre = x @ Wi^T  (bf16 MFMA 16x16x32, 128x128 tiles).
// Phase 1.5: in-place row LN (scale=b1, shift=s1) over the 2048 gate dim.
// Phase 2: persistent recurrence. 64 wgs = 4 teams(16 samples) x 16 slices.
//   Sync redesign vs R0: per-wg flag WORDS (no atomic RMW), relaxed polls
//   (no per-poll cache invalidate), single acquire fence on success,
//   per-team-per-hop flag lines 1KB apart, XCD-aware block swizzle.

typedef float  f32x4 __attribute__((ext_vector_type(4)));
typedef __bf16 bf16x8 __attribute__((ext_vector_type(8)));
typedef unsigned int u32x4 __attribute__((ext_vector_type(4)));
typedef unsigned short u16x4 __attribute__((ext_vector_type(4)));

#define DEV __device__ __forceinline__

DEV unsigned short f2b(float f){
  unsigned int u = __builtin_bit_cast(unsigned int, f);
  unsigned int r = (u + 0x7FFFu + ((u >> 16) & 1u)) >> 16;
  return (unsigned short)r;
}
DEV float b2f(unsigned short s){
  unsigned int u = ((unsigned int)s) << 16;
  return __builtin_bit_cast(float, u);
}

// Poll 16 per-wg flag words (one 64B line) with RELAXED loads; one acquire
// fence on success. Must be called by a full wave.
DEV void poll16(unsigned int* f, unsigned int target){
  const int l = threadIdx.x & 63;
  unsigned int v = 0xFFFFFFFFu;
  for (;;){
    if (l < 16) v = __hip_atomic_load(f + l, __ATOMIC_RELAXED, __HIP_MEMORY_SCOPE_AGENT);
    if (__all((int)(l >= 16 || v >= target))) break;
  }
  __builtin_amdgcn_fence(__ATOMIC_ACQUIRE, "agent");
}

// ---------------- Phase 0: conversion ----------------
__global__ __launch_bounds__(256) void conv_bf16(const float* __restrict__ src,
                                                 unsigned short* __restrict__ dst,
                                                 int n4){
  int i = blockIdx.x * 256 + threadIdx.x;
  if (i >= n4) return;
  f32x4 v = ((const f32x4*)src)[i];
  u16x4 o;
  #pragma unroll
  for (int j = 0; j < 4; ++j) o[j] = f2b(v[j]);
  ((u16x4*)dst)[i] = o;
}

// ---------------- Phase 1: Gpre = Xb @ Wib^T ----------------
__global__ __launch_bounds__(256, 2) void gemm_gi(const unsigned short* __restrict__ Xb,
                                                  const unsigned short* __restrict__ Wib,
                                                  unsigned short* __restrict__ Gp){
  __shared__ unsigned short As[128 * 48];
  __shared__ unsigned short Bs[128 * 48];
  const int tid = threadIdx.x;
  const int m0 = blockIdx.x * 128;
  const int n0 = blockIdx.y * 128;
  const int w = tid >> 6, lane = tid & 63;
  const int lr = lane & 15, lq = lane >> 4;
  const int wm = (w & 1) * 64, wn = (w >> 1) * 64;
  const int sr = tid >> 2;
  const int sc = (tid & 3) * 8;
  const unsigned short* gx = Xb + (size_t)(m0 + sr) * 512 + sc;
  const unsigned short* gw = Wib + (size_t)(n0 + sr) * 512 + sc;
  f32x4 acc[4][4] = {};
  for (int kb = 0; kb < 16; ++kb){
    u32x4 a0 = *(const u32x4*)(gx + kb * 32);
    u32x4 a1 = *(const u32x4*)(gx + 64 * 512 + kb * 32);
    u32x4 b0 = *(const u32x4*)(gw + kb * 32);
    u32x4 b1 = *(const u32x4*)(gw + 64 * 512 + kb * 32);
    __syncthreads();
    *(u32x4*)&As[sr * 48 + sc] = a0;
    *(u32x4*)&As[(sr + 64) * 48 + sc] = a1;
    *(u32x4*)&Bs[sr * 48 + sc] = b0;
    *(u32x4*)&Bs[(sr + 64) * 48 + sc] = b1;
    __syncthreads();
    bf16x8 af[4], bfv[4];
    #pragma unroll
    for (int mi = 0; mi < 4; ++mi) af[mi] = *(const bf16x8*)&As[(wm + mi * 16 + lr) * 48 + lq * 8];
    #pragma unroll
    for (int ni = 0; ni < 4; ++ni) bfv[ni] = *(const bf16x8*)&Bs[(wn + ni * 16 + lr) * 48 + lq * 8];
    #pragma unroll
    for (int mi = 0; mi < 4; ++mi)
      #pragma unroll
      for (int ni = 0; ni < 4; ++ni)
        acc[mi][ni] = __builtin_amdgcn_mfma_f32_16x16x32_bf16(af[mi], bfv[ni], acc[mi][ni], 0, 0, 0);
  }
  #pragma unroll
  for (int mi = 0; mi < 4; ++mi){
    const int rowb = m0 + wm + mi * 16 + lq * 4;
    #pragma unroll
    for (int ni = 0; ni < 4; ++ni){
      const int col = n0 + wn + ni * 16 + lr;
      #pragma unroll
      for (int r = 0; r < 4; ++r)
        Gp[(size_t)(rowb + r) * 2048 + col] = f2b(acc[mi][ni][r]);
    }
  }
}

// ---------------- Phase 1.5: row LN (scale=b1, shift=s1) ----------------
__global__ __launch_bounds__(256) void ln_rows(unsigned short* __restrict__ G,
                                               const float* __restrict__ b1,
                                               const float* __restrict__ s1){
  const int row = blockIdx.x;
  const int tid = threadIdx.x;
  unsigned short* rp = G + (size_t)row * 2048 + tid * 8;
  u32x4 raw = *(const u32x4*)rp;
  float x[8];
  #pragma unroll
  for (int j = 0; j < 8; ++j){
    unsigned int word = raw[j >> 1];
    unsigned short us = (j & 1) ? (unsigned short)(word >> 16) : (unsigned short)(word & 0xFFFF);
    x[j] = b2f(us);
  }
  float s = 0.f, q = 0.f;
  #pragma unroll
  for (int j = 0; j < 8; ++j){ s += x[j]; q += x[j] * x[j]; }
  #pragma unroll
  for (int o = 1; o < 64; o <<= 1){ s += __shfl_xor(s, o); q += __shfl_xor(q, o); }
  __shared__ float ps[4][2];
  const int wv = tid >> 6;
  if ((tid & 63) == 0){ ps[wv][0] = s; ps[wv][1] = q; }
  __syncthreads();
  s = ps[0][0] + ps[1][0] + ps[2][0] + ps[3][0];
  q = ps[0][1] + ps[1][1] + ps[2][1] + ps[3][1];
  const float mu = s * (1.f / 2048.f);
  const float inv = rsqrtf((q - s * mu) + 1e-5f);
  const float* b1p = b1 + tid * 8;
  const float* s1p = s1 + tid * 8;
  u32x4 outw;
  #pragma unroll
  for (int j = 0; j < 4; ++j){
    float y0 = b1p[2 * j]     * ((x[2 * j]     - mu) * inv) + s1p[2 * j];
    float y1 = b1p[2 * j + 1] * ((x[2 * j + 1] - mu) * inv) + s1p[2 * j + 1];
    outw[j] = (unsigned int)f2b(y0) | ((unsigned int)f2b(y1) << 16);
  }
  *(u32x4*)rp = outw;
}

// ---------------- Phase 2: persistent recurrence ----------------
__global__ __launch_bounds__(512, 2) void lstm_rec(
    const unsigned short* __restrict__ Gi,   // [32768][2048] bf16, post-LN gi
    const unsigned short* __restrict__ Whb,  // [2048][512] bf16
    const float* __restrict__ bias,
    const float* __restrict__ b2, const float* __restrict__ s2,
    const float* __restrict__ b3, const float* __restrict__ s3,
    const float* __restrict__ cx,
    unsigned short* __restrict__ hb,         // [2][64][512] bf16
    float* __restrict__ stA,                 // [2][4][16][16][2]
    float* __restrict__ stC,                 // [2][4][16][16][2]
    unsigned int* __restrict__ F,            // flags: [hop 3][team 4][256 u32]
    float* __restrict__ out){
  const int tid = threadIdx.x;
  // XCD-aware swizzle: team tm's 16 wgs land on 2 XCDs (blockIdx round-robin).
  const int tm = (blockIdx.x >> 1) & 3;
  const int ks = ((blockIdx.x >> 3) << 1) | (blockIdx.x & 1);
  const int w = tid >> 6;
  const int lane = tid & 63;
  const int lr = lane & 15, lq = lane >> 4;

  unsigned int* fH = F + (0 * 4 + tm) * 256;
  unsigned int* fA = F + (4 + tm) * 256;
  unsigned int* fC = F + (8 + tm) * 256;

  // gate-wave constants
  const int type = w >> 1;                 // 0=i 1=f 2=g 3=o
  const int jloc = (w & 1) * 16 + lr;      // 0..31
  const int row_g = type * 512 + ks * 32 + jloc;
  const float b2r = b2[row_g];
  const float sbr = s2[row_g] + bias[row_g];

  // Wh B-fragments in registers
  bf16x8 bfr[16];
  {
    const unsigned short* wr = Whb + (size_t)row_g * 512 + lq * 8;
    #pragma unroll
    for (int kk = 0; kk < 16; ++kk) bfr[kk] = *(const bf16x8*)(wr + kk * 32);
  }

  // c-phase constants: sample = tid>>5, col = tid&31 (coalesced stores)
  const int cs = tid >> 5;                 // 0..15
  const int cj = tid & 31;                 // 0..31
  const int hcol = ks * 32 + cj;
  const int bidx = tm * 16 + cs;
  float c_val = cx[(size_t)bidx * 512 + hcol];
  const float b3j = b3[hcol], s3j = s3[hcol];

  __shared__ float act[4][32][17];
  __shared__ float redA[8][16][2];
  __shared__ float redC[16][2];
  __shared__ float stAl[16][2];
  __shared__ float stCl[16][2];

  for (int t = 0; t < 512; ++t){
    const int par = t & 1;
    // gi prefetch (overlaps the H poll)
    float giv[4];
    #pragma unroll
    for (int r = 0; r < 4; ++r){
      const int b = tm * 16 + lq * 4 + r;
      giv[r] = b2f(Gi[((size_t)b * 512 + t) * 2048 + row_g]);
    }
    // ---- hop H: wait for h(t); every wave polls + acquires ----
    poll16(fH, (unsigned)t);
    const unsigned short* hp = hb + par * 32768 + (size_t)(tm * 16 + lr) * 512 + lq * 8;
    bf16x8 af[16];
    #pragma unroll
    for (int kk = 0; kk < 16; ++kk) af[kk] = *(const bf16x8*)(hp + kk * 32);
    f32x4 acc = {0.f, 0.f, 0.f, 0.f};
    #pragma unroll
    for (int kk = 0; kk < 16; ++kk)
      acc = __builtin_amdgcn_mfma_f32_16x16x32_bf16(af[kk], bfr[kk], acc, 0, 0, 0);
    // per-sample partial (s,q) over this wave's 16 gate cols
    #pragma unroll
    for (int r = 0; r < 4; ++r){
      float s = acc[r], q = acc[r] * acc[r];
      #pragma unroll
      for (int o = 1; o < 16; o <<= 1){ s += __shfl_xor(s, o); q += __shfl_xor(q, o); }
      if (lr == 0){ redA[w][lq * 4 + r][0] = s; redA[w][lq * 4 + r][1] = q; }
    }
    __syncthreads();                                   // S1
    // ---- hop A: gate-LN stats ----
    float* slotA = stA + (size_t)(par * 4 + tm) * 512;
    if (w == 0){
      if (tid < 16){
        float S = 0.f, Q = 0.f;
        #pragma unroll
        for (int w2 = 0; w2 < 8; ++w2){ S += redA[w2][tid][0]; Q += redA[w2][tid][1]; }
        slotA[(tid * 16 + ks) * 2 + 0] = S;
        slotA[(tid * 16 + ks) * 2 + 1] = Q;
      }
      if (tid == 0)
        __hip_atomic_store(fA + ks, (unsigned)(t + 1), __ATOMIC_RELEASE, __HIP_MEMORY_SCOPE_AGENT);
      poll16(fA, (unsigned)(t + 1));
      if (tid < 16){
        float S = 0.f, Q = 0.f;
        #pragma unroll
        for (int k2 = 0; k2 < 16; ++k2){ S += slotA[(tid * 16 + k2) * 2]; Q += slotA[(tid * 16 + k2) * 2 + 1]; }
        const float mu = S * (1.f / 2048.f);
        stAl[tid][0] = mu;
        stAl[tid][1] = rsqrtf((Q - S * mu) + 1e-5f);
      }
    }
    __syncthreads();                                   // S2
    // gates + activations
    #pragma unroll
    for (int r = 0; r < 4; ++r){
      const int s0 = lq * 4 + r;
      const float nv = (acc[r] - stAl[s0][0]) * stAl[s0][1];
      const float gv = giv[r] + b2r * nv + sbr;
      float a;
      if (type == 2) a = tanhf(gv);
      else           a = 1.f / (1.f + __expf(-gv));
      act[type][jloc][s0] = a;
    }
    __syncthreads();                                   // S3
    // c-candidate + per-sample stats (one wave covers 2 full samples)
    const float i_g = act[0][cj][cs];
    const float f_g = act[1][cj][cs];
    const float g_g = act[2][cj][cs];
    const float o_g = act[3][cj][cs];
    const float cc = f_g * c_val + i_g * g_g;
    {
      float s = cc, q = cc * cc;
      #pragma unroll
      for (int o = 1; o < 32; o <<= 1){ s += __shfl_xor(s, o); q += __shfl_xor(q, o); }
      if ((lane & 31) == 0){ redC[cs][0] = s; redC[cs][1] = q; }
    }
    __syncthreads();                                   // S4
    // ---- hop C: c-LN stats ----
    float* slotC = stC + (size_t)(par * 4 + tm) * 512;
    if (w == 0){
      if (tid < 16){
        slotC[(tid * 16 + ks) * 2 + 0] = redC[tid][0];
        slotC[(tid * 16 + ks) * 2 + 1] = redC[tid][1];
      }
      if (tid == 0)
        __hip_atomic_store(fC + ks, (unsigned)(t + 1), __ATOMIC_RELEASE, __HIP_MEMORY_SCOPE_AGENT);
      poll16(fC, (unsigned)(t + 1));
      if (tid < 16){
        float S = 0.f, Q = 0.f;
        #pragma unroll
        for (int k2 = 0; k2 < 16; ++k2){ S += slotC[(tid * 16 + k2) * 2]; Q += slotC[(tid * 16 + k2) * 2 + 1]; }
        const float mu = S * (1.f / 512.f);
        stCl[tid][0] = mu;
        stCl[tid][1] = rsqrtf((Q - S * mu) + 1e-5f);
      }
    }
    __syncthreads();                                   // S5
    const float cn = b3j * ((cc - stCl[cs][0]) * stCl[cs][1]) + s3j;
    c_val = cn;
    const float h = o_g * tanhf(cn);
    out[((size_t)bidx * 512 + t) * 512 + hcol] = h;
    if (t == 511){
      out[16777216u + (size_t)bidx * 512 + hcol] = h;
      out[16777216u + 32768u + (size_t)bidx * 512 + hcol] = cn;
    }
    hb[(1 - par) * 32768 + (size_t)bidx * 512 + hcol] = f2b(h);
    // make this wave's hb stores visible, then (after all waves) post flag
    __builtin_amdgcn_fence(__ATOMIC_RELEASE, "agent");
    __syncthreads();                                   // S6
    if (tid == 0)
      __hip_atomic_store(fH + ks, (unsigned)(t + 1), __ATOMIC_RELEASE, __HIP_MEMORY_SCOPE_AGENT);
  }
}

extern "C" void kernel_launch(void* const* d_in, const int* in_sizes, int n_in,
                              void* d_out, int out_size, void* d_ws, size_t ws_size,
                              hipStream_t stream){
  (void)in_sizes; (void)n_in; (void)out_size; (void)ws_size;
  const float* x    = (const float*)d_in[0];
  const float* hx   = (const float*)d_in[1];
  const float* cx   = (const float*)d_in[2];
  const float* Wi   = (const float*)d_in[3];
  const float* Wh   = (const float*)d_in[4];
  const float* bias = (const float*)d_in[5];
  const float* b1   = (const float*)d_in[6];
  const float* b2   = (const float*)d_in[7];
  const float* b3   = (const float*)d_in[8];
  const float* s1   = (const float*)d_in[9];
  const float* s2   = (const float*)d_in[10];
  const float* s3   = (const float*)d_in[11];
  float* out = (float*)d_out;
  char* ws = (char*)d_ws;

  unsigned short* xb  = (unsigned short*)(ws);                 // 33,554,432 B
  unsigned short* wib = (unsigned short*)(ws + 33554432);      //  2,097,152 B
  unsigned short* whb = (unsigned short*)(ws + 35651584);      //  2,097,152 B
  unsigned short* gp  = (unsigned short*)(ws + 37748736);      // 134,217,728 B
  unsigned short* hb  = (unsigned short*)(ws + 171966464);     //    131,072 B
  float*        stA   = (float*)(ws + 172097536);              //     16,384 B
  float*        stC   = (float*)(ws + 172113920);              //     16,384 B
  unsigned int* flg   = (unsigned int*)(ws + 172130304);       //     12,288 B

  conv_bf16<<<16384, 256, 0, stream>>>(x,  xb,  4194304);
  conv_bf16<<<1024,  256, 0, stream>>>(Wi, wib, 262144);
  conv_bf16<<<1024,  256, 0, stream>>>(Wh, whb, 262144);
  conv_bf16<<<32,    256, 0, stream>>>(hx, hb,  8192);   // h(0) slot
  hipMemsetAsync(flg, 0, 12288, stream);
  gemm_gi<<<dim3(256, 16, 1), 256, 0, stream>>>(xb, wib, gp);
  ln_rows<<<32768, 256, 0, stream>>>(gp, b1, s1);
  lstm_rec<<<64, 512, 0, stream>>>(gp, whb, bias, b2, s2, b3, s3, cx,
                                   hb, stA, stC, flg, out);
}

// Round 3
// 3821.709 us; speedup vs baseline: 4.8131x; 3.2375x over previous
//
#include <hip/hip_runtime.h>
#include <cstdint>
#include <cstddef>

// LayerNormLSTM on MI355X.
// Phase 0: fp32->bf16 conversion of x, Wi, Wh; tagged init of h(0).
// Phase 1: Gpre = x @ Wi^T  (bf16 MFMA 16x16x32, 128x128 tiles).
// Phase 1.5: in-place row LN (scale=b1, shift=s1) over the 2048 gate dim.
// Phase 2: persistent recurrence, 64 wgs = 4 teams(16 samples) x 16 slices.
//   R3 sync: ZERO cache-maintenance fences in the loop. All cross-wg data via
//   agent-scope RELAXED atomics (sc1: bypass L1/L2, operate at MALL):
//    - LN stats: MALL-side f32 atomicAdd into per-step fresh slots (no reuse),
//      ordering via s_waitcnt vmcnt(0) before the counter increment.
//    - h broadcast: tag-embedded u64 (tag<<32 | 2 bf16), parity buffers.

typedef float  f32x4 __attribute__((ext_vector_type(4)));
typedef __bf16 bf16x8 __attribute__((ext_vector_type(8)));
typedef unsigned int u32x4 __attribute__((ext_vector_type(4)));
typedef unsigned short u16x4 __attribute__((ext_vector_type(4)));

#define DEV __device__ __forceinline__
// wait vmcnt(0), ignore exp/lgkm; signal fences pin compiler ordering
#define WAITCNT_VM0() do{ __atomic_signal_fence(__ATOMIC_SEQ_CST); \
  __builtin_amdgcn_s_waitcnt(0x0F70); \
  __atomic_signal_fence(__ATOMIC_SEQ_CST);}while(0)

DEV unsigned short f2b(float f){
  unsigned int u = __builtin_bit_cast(unsigned int, f);
  unsigned int r = (u + 0x7FFFu + ((u >> 16) & 1u)) >> 16;
  return (unsigned short)r;
}
DEV float b2f(unsigned short s){
  unsigned int u = ((unsigned int)s) << 16;
  return __builtin_bit_cast(float, u);
}

// ---------------- Phase 0: conversion ----------------
__global__ __launch_bounds__(256) void conv_bf16(const float* __restrict__ src,
                                                 unsigned short* __restrict__ dst,
                                                 int n4){
  int i = blockIdx.x * 256 + threadIdx.x;
  if (i >= n4) return;
  f32x4 v = ((const f32x4*)src)[i];
  u16x4 o;
  #pragma unroll
  for (int j = 0; j < 4; ++j) o[j] = f2b(v[j]);
  ((u16x4*)dst)[i] = o;
}

// h(0): tagged u64 format, tag=0
__global__ __launch_bounds__(256) void init_h(const float* __restrict__ hx,
                                              unsigned long long* __restrict__ hbuf){
  int s = blockIdx.x;        // 0..63
  int p = threadIdx.x;       // 0..255
  float h0 = hx[s * 512 + 2 * p];
  float h1 = hx[s * 512 + 2 * p + 1];
  unsigned long long v = (unsigned long long)f2b(h0) |
                         ((unsigned long long)f2b(h1) << 16);
  hbuf[(size_t)s * 256 + p] = v;
}

// ---------------- Phase 1: Gpre = Xb @ Wib^T ----------------
__global__ __launch_bounds__(256, 2) void gemm_gi(const unsigned short* __restrict__ Xb,
                                                  const unsigned short* __restrict__ Wib,
                                                  unsigned short* __restrict__ Gp){
  __shared__ unsigned short As[128 * 48];
  __shared__ unsigned short Bs[128 * 48];
  const int tid = threadIdx.x;
  const int m0 = blockIdx.x * 128;
  const int n0 = blockIdx.y * 128;
  const int w = tid >> 6, lane = tid & 63;
  const int lr = lane & 15, lq = lane >> 4;
  const int wm = (w & 1) * 64, wn = (w >> 1) * 64;
  const int sr = tid >> 2;
  const int sc = (tid & 3) * 8;
  const unsigned short* gx = Xb + (size_t)(m0 + sr) * 512 + sc;
  const unsigned short* gw = Wib + (size_t)(n0 + sr) * 512 + sc;
  f32x4 acc[4][4] = {};
  for (int kb = 0; kb < 16; ++kb){
    u32x4 a0 = *(const u32x4*)(gx + kb * 32);
    u32x4 a1 = *(const u32x4*)(gx + 64 * 512 + kb * 32);
    u32x4 b0 = *(const u32x4*)(gw + kb * 32);
    u32x4 b1 = *(const u32x4*)(gw + 64 * 512 + kb * 32);
    __syncthreads();
    *(u32x4*)&As[sr * 48 + sc] = a0;
    *(u32x4*)&As[(sr + 64) * 48 + sc] = a1;
    *(u32x4*)&Bs[sr * 48 + sc] = b0;
    *(u32x4*)&Bs[(sr + 64) * 48 + sc] = b1;
    __syncthreads();
    bf16x8 af[4], bfv[4];
    #pragma unroll
    for (int mi = 0; mi < 4; ++mi) af[mi] = *(const bf16x8*)&As[(wm + mi * 16 + lr) * 48 + lq * 8];
    #pragma unroll
    for (int ni = 0; ni < 4; ++ni) bfv[ni] = *(const bf16x8*)&Bs[(wn + ni * 16 + lr) * 48 + lq * 8];
    #pragma unroll
    for (int mi = 0; mi < 4; ++mi)
      #pragma unroll
      for (int ni = 0; ni < 4; ++ni)
        acc[mi][ni] = __builtin_amdgcn_mfma_f32_16x16x32_bf16(af[mi], bfv[ni], acc[mi][ni], 0, 0, 0);
  }
  #pragma unroll
  for (int mi = 0; mi < 4; ++mi){
    const int rowb = m0 + wm + mi * 16 + lq * 4;
    #pragma unroll
    for (int ni = 0; ni < 4; ++ni){
      const int col = n0 + wn + ni * 16 + lr;
      #pragma unroll
      for (int r = 0; r < 4; ++r)
        Gp[(size_t)(rowb + r) * 2048 + col] = f2b(acc[mi][ni][r]);
    }
  }
}

// ---------------- Phase 1.5: row LN (scale=b1, shift=s1) ----------------
__global__ __launch_bounds__(256) void ln_rows(unsigned short* __restrict__ G,
                                               const float* __restrict__ b1,
                                               const float* __restrict__ s1){
  const int row = blockIdx.x;
  const int tid = threadIdx.x;
  unsigned short* rp = G + (size_t)row * 2048 + tid * 8;
  u32x4 raw = *(const u32x4*)rp;
  float x[8];
  #pragma unroll
  for (int j = 0; j < 8; ++j){
    unsigned int word = raw[j >> 1];
    unsigned short us = (j & 1) ? (unsigned short)(word >> 16) : (unsigned short)(word & 0xFFFF);
    x[j] = b2f(us);
  }
  float s = 0.f, q = 0.f;
  #pragma unroll
  for (int j = 0; j < 8; ++j){ s += x[j]; q += x[j] * x[j]; }
  #pragma unroll
  for (int o = 1; o < 64; o <<= 1){ s += __shfl_xor(s, o); q += __shfl_xor(q, o); }
  __shared__ float ps[4][2];
  const int wv = tid >> 6;
  if ((tid & 63) == 0){ ps[wv][0] = s; ps[wv][1] = q; }
  __syncthreads();
  s = ps[0][0] + ps[1][0] + ps[2][0] + ps[3][0];
  q = ps[0][1] + ps[1][1] + ps[2][1] + ps[3][1];
  const float mu = s * (1.f / 2048.f);
  const float inv = rsqrtf((q - s * mu) + 1e-5f);
  const float* b1p = b1 + tid * 8;
  const float* s1p = s1 + tid * 8;
  u32x4 outw;
  #pragma unroll
  for (int j = 0; j < 4; ++j){
    float y0 = b1p[2 * j]     * ((x[2 * j]     - mu) * inv) + s1p[2 * j];
    float y1 = b1p[2 * j + 1] * ((x[2 * j + 1] - mu) * inv) + s1p[2 * j + 1];
    outw[j] = (unsigned int)f2b(y0) | ((unsigned int)f2b(y1) << 16);
  }
  *(u32x4*)rp = outw;
}

// ---------------- Phase 2: persistent recurrence ----------------
__global__ __launch_bounds__(512, 2) void lstm_rec(
    const unsigned short* __restrict__ Gi,   // [32768][2048] bf16, post-LN gi
    const unsigned short* __restrict__ Whb,  // [2048][512] bf16
    const float* __restrict__ bias,
    const float* __restrict__ b2, const float* __restrict__ s2,
    const float* __restrict__ b3, const float* __restrict__ s3,
    const float* __restrict__ cx,
    unsigned long long* __restrict__ hbuf,   // [2][64][256] tagged u64
    float* __restrict__ stA,                 // [512][4][16][2] f32, zeroed
    float* __restrict__ stC,                 // [512][4][16][2] f32, zeroed
    unsigned int* __restrict__ cntA,         // [512][4], zeroed
    unsigned int* __restrict__ cntC,         // [512][4], zeroed
    float* __restrict__ out){
  const int tid = threadIdx.x;
  const int tm = (blockIdx.x >> 1) & 3;                  // team
  const int ks = ((blockIdx.x >> 3) << 1) | (blockIdx.x & 1);  // slice
  const int w = tid >> 6;
  const int lane = tid & 63;
  const int lr = lane & 15, lq = lane >> 4;

  // gate-wave constants: wave w owns gate rows type*512 + ks*32 + jloc
  const int type = w >> 1;
  const int jloc = (w & 1) * 16 + lr;
  const int row_g = type * 512 + ks * 32 + jloc;
  const float b2r = b2[row_g];
  const float sbr = s2[row_g] + bias[row_g];

  // Wh B-fragments in registers
  bf16x8 bfr[16];
  {
    const unsigned short* wr = Whb + (size_t)row_g * 512 + lq * 8;
    #pragma unroll
    for (int kk = 0; kk < 16; ++kk) bfr[kk] = *(const bf16x8*)(wr + kk * 32);
  }

  // c-phase constants
  const int cs = tid >> 5;                 // team sample 0..15
  const int cj = tid & 31;                 // col within slice
  const int hcol = ks * 32 + cj;
  const int bidx = tm * 16 + cs;
  float c_val = cx[(size_t)bidx * 512 + hcol];
  const float b3j = b3[hcol], s3j = s3[hcol];

  // H-poll slice: wave w covers team samples 2w, 2w+1
  const int psmp = 2 * w + (lane >> 5);    // 0..15
  const int pidx = lane & 31;              // u64 index stride base

  __shared__ unsigned short hlds[16 * 520];   // padded: 2-way bank alias only
  __shared__ float act[4][32][17];
  __shared__ float redA[8][16][2];
  __shared__ float redC[16][2];
  __shared__ float stAl[16][2];
  __shared__ float stCl[16][2];

  for (int t = 0; t < 512; ++t){
    // gi prefetch (in flight during the H poll)
    float giv[4];
    #pragma unroll
    for (int r = 0; r < 4; ++r){
      const int b = tm * 16 + lq * 4 + r;
      giv[r] = b2f(Gi[((size_t)b * 512 + t) * 2048 + row_g]);
    }

    // ---- hop H: tagged-u64 poll of this wave's 2-sample slice ----
    const unsigned long long* hsrc =
        hbuf + (size_t)(t & 1) * 16384 + (size_t)(tm * 16 + psmp) * 256;
    unsigned long long hv[8];
    for (;;){
      bool ok = true;
      #pragma unroll
      for (int j = 0; j < 8; ++j)
        hv[j] = __hip_atomic_load(hsrc + pidx + 32 * j, __ATOMIC_RELAXED, __HIP_MEMORY_SCOPE_AGENT);
      #pragma unroll
      for (int j = 0; j < 8; ++j) ok &= ((unsigned)(hv[j] >> 32) == (unsigned)t);
      if (__all((int)ok)) break;
    }
    #pragma unroll
    for (int j = 0; j < 8; ++j)
      *(unsigned int*)&hlds[psmp * 520 + 2 * (pidx + 32 * j)] = (unsigned)hv[j];
    __syncthreads();                                   // S1

    // A-frags from LDS; MFMA over K=512
    f32x4 acc = {0.f, 0.f, 0.f, 0.f};
    #pragma unroll
    for (int kk = 0; kk < 16; ++kk){
      bf16x8 af = *(const bf16x8*)&hlds[lr * 520 + lq * 8 + kk * 32];
      acc = __builtin_amdgcn_mfma_f32_16x16x32_bf16(af, bfr[kk], acc, 0, 0, 0);
    }
    // per-sample partial (s,q) over this wave's 16 gate cols
    #pragma unroll
    for (int r = 0; r < 4; ++r){
      float s = acc[r], q = acc[r] * acc[r];
      #pragma unroll
      for (int o = 1; o < 16; o <<= 1){ s += __shfl_xor(s, o); q += __shfl_xor(q, o); }
      if (lr == 0){ redA[w][lq * 4 + r][0] = s; redA[w][lq * 4 + r][1] = q; }
    }
    __syncthreads();                                   // S2

    // ---- hop A: MALL atomic-add stats, fresh per-step slot ----
    float* slotA = stA + ((size_t)t * 4 + tm) * 32;
    unsigned int* cA = cntA + t * 4 + tm;
    if (w == 0){
      float S = 0.f, Q = 0.f;
      if (lane < 16){
        #pragma unroll
        for (int w2 = 0; w2 < 8; ++w2){ S += redA[w2][lane][0]; Q += redA[w2][lane][1]; }
      }
      float Sv = __shfl(S, lane >> 1);
      float Qv = __shfl(Q, lane >> 1);
      float addv = (lane & 1) ? Qv : Sv;
      if (lane < 32)
        __hip_atomic_fetch_add(slotA + lane, addv, __ATOMIC_RELAXED, __HIP_MEMORY_SCOPE_AGENT);
      WAITCNT_VM0();
      if (lane == 0)
        __hip_atomic_fetch_add(cA, 1u, __ATOMIC_RELAXED, __HIP_MEMORY_SCOPE_AGENT);
      for (;;){
        unsigned int c = __hip_atomic_load(cA, __ATOMIC_RELAXED, __HIP_MEMORY_SCOPE_AGENT);
        if (c >= 16u) break;
      }
      float fv = 0.f;
      if (lane < 32)
        fv = __hip_atomic_load(slotA + lane, __ATOMIC_RELAXED, __HIP_MEMORY_SCOPE_AGENT);
      float Ssum = __shfl(fv, 2 * lane);
      float Qsum = __shfl(fv, 2 * lane + 1);
      if (lane < 16){
        const float mu = Ssum * (1.f / 2048.f);
        stAl[lane][0] = mu;
        stAl[lane][1] = rsqrtf((Qsum - Ssum * mu) + 1e-5f);
      }
    }
    __syncthreads();                                   // S3

    // gates + activations
    #pragma unroll
    for (int r = 0; r < 4; ++r){
      const int s0 = lq * 4 + r;
      const float nv = (acc[r] - stAl[s0][0]) * stAl[s0][1];
      const float gv = giv[r] + b2r * nv + sbr;
      float a;
      if (type == 2) a = tanhf(gv);
      else           a = 1.f / (1.f + __expf(-gv));
      act[type][jloc][s0] = a;
    }
    __syncthreads();                                   // S4

    // c-candidate + per-sample stats
    const float i_g = act[0][cj][cs];
    const float f_g = act[1][cj][cs];
    const float g_g = act[2][cj][cs];
    const float o_g = act[3][cj][cs];
    const float cc = f_g * c_val + i_g * g_g;
    {
      float s = cc, q = cc * cc;
      #pragma unroll
      for (int o = 1; o < 32; o <<= 1){ s += __shfl_xor(s, o); q += __shfl_xor(q, o); }
      if ((lane & 31) == 0){ redC[cs][0] = s; redC[cs][1] = q; }
    }
    __syncthreads();                                   // S5

    // ---- hop C ----
    float* slotC = stC + ((size_t)t * 4 + tm) * 32;
    unsigned int* cC = cntC + t * 4 + tm;
    if (w == 0){
      float v = 0.f;
      if (lane < 32) v = (lane & 1) ? redC[lane >> 1][1] : redC[lane >> 1][0];
      if (lane < 32)
        __hip_atomic_fetch_add(slotC + lane, v, __ATOMIC_RELAXED, __HIP_MEMORY_SCOPE_AGENT);
      WAITCNT_VM0();
      if (lane == 0)
        __hip_atomic_fetch_add(cC, 1u, __ATOMIC_RELAXED, __HIP_MEMORY_SCOPE_AGENT);
      for (;;){
        unsigned int c = __hip_atomic_load(cC, __ATOMIC_RELAXED, __HIP_MEMORY_SCOPE_AGENT);
        if (c >= 16u) break;
      }
      float fv = 0.f;
      if (lane < 32)
        fv = __hip_atomic_load(slotC + lane, __ATOMIC_RELAXED, __HIP_MEMORY_SCOPE_AGENT);
      float Ssum = __shfl(fv, 2 * lane);
      float Qsum = __shfl(fv, 2 * lane + 1);
      if (lane < 16){
        const float mu = Ssum * (1.f / 512.f);
        stCl[lane][0] = mu;
        stCl[lane][1] = rsqrtf((Qsum - Ssum * mu) + 1e-5f);
      }
    }
    __syncthreads();                                   // S6

    const float cn = b3j * ((cc - stCl[cs][0]) * stCl[cs][1]) + s3j;
    c_val = cn;
    const float h = o_g * tanhf(cn);
    out[((size_t)bidx * 512 + t) * 512 + hcol] = h;
    if (t == 511){
      out[16777216u + (size_t)bidx * 512 + hcol] = h;
      out[16777216u + 32768u + (size_t)bidx * 512 + hcol] = cn;
    }
    // ---- post h(t+1): tagged u64, no fence needed ----
    const float hpair = __shfl_xor(h, 1);
    if ((lane & 1) == 0){
      unsigned long long pv = ((unsigned long long)(unsigned)(t + 1) << 32) |
                              (unsigned long long)f2b(h) |
                              ((unsigned long long)f2b(hpair) << 16);
      __hip_atomic_store(hbuf + (size_t)((t + 1) & 1) * 16384 +
                             (size_t)bidx * 256 + (hcol >> 1),
                         pv, __ATOMIC_RELAXED, __HIP_MEMORY_SCOPE_AGENT);
    }
  }
}

extern "C" void kernel_launch(void* const* d_in, const int* in_sizes, int n_in,
                              void* d_out, int out_size, void* d_ws, size_t ws_size,
                              hipStream_t stream){
  (void)in_sizes; (void)n_in; (void)out_size; (void)ws_size;
  const float* x    = (const float*)d_in[0];
  const float* hx   = (const float*)d_in[1];
  const float* cx   = (const float*)d_in[2];
  const float* Wi   = (const float*)d_in[3];
  const float* Wh   = (const float*)d_in[4];
  const float* bias = (const float*)d_in[5];
  const float* b1   = (const float*)d_in[6];
  const float* b2   = (const float*)d_in[7];
  const float* b3   = (const float*)d_in[8];
  const float* s1   = (const float*)d_in[9];
  const float* s2   = (const float*)d_in[10];
  const float* s3   = (const float*)d_in[11];
  float* out = (float*)d_out;
  char* ws = (char*)d_ws;

  unsigned short*     xb   = (unsigned short*)(ws);                 // 33,554,432
  unsigned short*     wib  = (unsigned short*)(ws + 33554432);      //  2,097,152
  unsigned short*     whb  = (unsigned short*)(ws + 35651584);      //  2,097,152
  unsigned short*     gp   = (unsigned short*)(ws + 37748736);      // 134,217,728
  unsigned long long* hbuf = (unsigned long long*)(ws + 171966464); //    262,144
  float*              stA  = (float*)(ws + 172228608);              //    262,144
  float*              stC  = (float*)(ws + 172490752);              //    262,144
  unsigned int*       cntA = (unsigned int*)(ws + 172752896);       //      8,192
  unsigned int*       cntC = (unsigned int*)(ws + 172761088);       //      8,192

  conv_bf16<<<16384, 256, 0, stream>>>(x,  xb,  4194304);
  conv_bf16<<<1024,  256, 0, stream>>>(Wi, wib, 262144);
  conv_bf16<<<1024,  256, 0, stream>>>(Wh, whb, 262144);
  init_h<<<64, 256, 0, stream>>>(hx, hbuf);
  hipMemsetAsync(stA, 0, 262144 + 262144 + 8192 + 8192, stream);  // stA..cntC contiguous
  gemm_gi<<<dim3(256, 16, 1), 256, 0, stream>>>(xb, wib, gp);
  ln_rows<<<32768, 256, 0, stream>>>(gp, b1, s1);
  lstm_rec<<<64, 512, 0, stream>>>(gp, whb, bias, b2, s2, b3, s3, cx,
                                   hbuf, stA, stC, cntA, cntC, out);
}